// Round 10
// baseline (173.951 us; speedup 1.0000x reference)
//
#include <hip/hip_runtime.h>

#define BN 4
#define CH 64          // CIN*UM = COUT*UM
#define HH 128
#define WW 128
#define PIX (HH*WW)

// workspace layout (float offsets)
#define OFF_WL  0                    // packed [8 ocg][64 c][9 tap][8 oc] = 36864
#define OFF_S   36864                // [2][64]      = 128
#define OFF_AVG 36992                // [4][2][128][128] = 131072

__device__ __forceinline__ int iclamp(int v, int lo, int hi) {
    return v < lo ? lo : (v > hi ? hi : v);
}

// ---- single prep kernel, 3 roles by block range:
//  [0,144)    : Wl packed [ocg][c][tap][8] ; ker[oc, c, p, q], tap = q*3+p
//  144        : S[u][oc] via factorized sum (== sum of ker over i,taps)
//  [145, 657) : avg[b][u][16x16 tile] via halo colsum + box3x3, /288
__global__ __launch_bounds__(256) void k_prep(const float* __restrict__ params,
                                              const float* __restrict__ basis,
                                              const float* __restrict__ x,
                                              float* __restrict__ Wl,
                                              float* __restrict__ S,
                                              float* __restrict__ avg) {
    int bx = blockIdx.x;
    if (bx < 144) {
        int idx = bx * 256 + threadIdx.x;      // < 36864
        int oc  = idx & 63;
        int tap = (idx >> 6) % 9;
        int c   = idx / 576;
        int q = tap / 3, p = tap % 3;
        int o = oc >> 1, g = oc & 1;
        int i = c >> 1, u = c & 1;
        float s = 0.f;
        #pragma unroll
        for (int n = 0; n < 4; ++n)
            #pragma unroll
            for (int d = 0; d < 4; ++d)
                s = fmaf(params[((o * 32 + i) * 4 + n) * 4 + d],
                         basis[((((n * 4 + d) * 3 + p) * 3 + q) * 2 + g) * 2 + u], s);
        // packed: [ocg][c][tap][oc&7]
        Wl[(((oc >> 3) * 64 + c) * 9 + tap) * 8 + (oc & 7)] = s;
    } else if (bx == 144) {
        int t = threadIdx.x;
        if (t < 128) {
            int u = t >> 6, oc = t & 63;
            int o = oc >> 1, g = oc & 1;
            float s = 0.f;
            #pragma unroll
            for (int nd = 0; nd < 16; ++nd) {
                int n = nd >> 2, d = nd & 3;
                float pa = 0.f;
                for (int i = 0; i < 32; ++i)
                    pa += params[((o * 32 + i) * 4 + n) * 4 + d];
                float sb = 0.f;
                #pragma unroll
                for (int e = 0; e < 3; ++e)
                    #pragma unroll
                    for (int f = 0; f < 3; ++f)
                        sb += basis[((((n * 4 + d) * 3 + e) * 3 + f) * 2 + g) * 2 + u];
                s = fmaf(pa, sb, s);
            }
            S[t] = s;
        }
    } else {
        // avg tile: id -> (b, u, tile)
        int id = bx - 145;                 // < 512
        int tile = id & 63;
        int u    = (id >> 6) & 1;
        int b    = id >> 7;
        int ty0 = (tile >> 3) * 16, tx0 = (tile & 7) * 16;

        __shared__ float hs[18][19];
        int t = threadIdx.x;
        for (int cell = t; cell < 324; cell += 256) {
            int hy = cell / 18, hx = cell - (cell / 18) * 18;
            int gy = iclamp(ty0 + hy - 1, 0, HH - 1);
            int gx = iclamp(tx0 + hx - 1, 0, WW - 1);
            const float* xp = x + ((size_t)b * CH + u) * PIX + gy * WW + gx;
            float s = 0.f;
            #pragma unroll
            for (int i = 0; i < 32; ++i) s += xp[(size_t)i * 2 * PIX];
            hs[hy][hx] = s;
        }
        __syncthreads();
        int py = t >> 4, px = t & 15;
        float s = hs[py][px]     + hs[py][px + 1]     + hs[py][px + 2]
                + hs[py + 1][px] + hs[py + 1][px + 1] + hs[py + 1][px + 2]
                + hs[py + 2][px] + hs[py + 2][px + 1] + hs[py + 2][px + 2];
        avg[(size_t)(b * 2 + u) * PIX + (ty0 + py) * WW + (tx0 + px)] = s * (1.0f / 288.0f);
    }
}

// ---- main: LDS halo staging (8 channels/round), 8 oc/thread, 32 waves/CU
__global__ __launch_bounds__(256, 8) void k_main(
    const float* __restrict__ x,     // [4][64][128][128]
    const float* __restrict__ Wl,    // packed [8][64][9][8]
    const float* __restrict__ S,     // [2][64]
    const float* __restrict__ bias,  // [64]
    const float* __restrict__ avg,   // [4][2][128][128]
    const float* __restrict__ bptr,  // scalar b
    float* __restrict__ out)         // [4][64][128][128]
{
    __shared__ float sm[8][18][18];   // 10368 B

    int tile = blockIdx.x;            // 8x8 tiles of 16x16
    int ocg  = blockIdx.y;            // 8 groups of 8 oc
    int b    = blockIdx.z;
    int ty = threadIdx.x >> 4, tx = threadIdx.x & 15;
    int h0 = (tile >> 3) * 16, w0 = (tile & 7) * 16;
    int h = h0 + ty, w = w0 + tx;

    float acc[8];
    #pragma unroll
    for (int j = 0; j < 8; ++j) acc[j] = 0.f;

    const float* xb = x + (size_t)b * CH * PIX;
    const float* wbase = Wl + (size_t)ocg * 64 * 72;   // [c][tap][8]

    for (int c0 = 0; c0 < CH; c0 += 8) {
        __syncthreads();   // protect sm reuse across rounds
        for (int cell = threadIdx.x; cell < 8 * 324; cell += 256) {
            int cc = cell / 324;
            int r  = cell - cc * 324;
            int hy = r / 18, hx = r - (r / 18) * 18;
            int gy = iclamp(h0 - 1 + hy, 0, HH - 1);
            int gx = iclamp(w0 - 1 + hx, 0, WW - 1);
            sm[cc][hy][hx] = xb[(size_t)(c0 + cc) * PIX + gy * WW + gx];
        }
        __syncthreads();

        const float* wc = wbase + c0 * 72;
        #pragma unroll
        for (int cc = 0; cc < 8; ++cc) {
            float xv[9];
            #pragma unroll
            for (int dy = 0; dy < 3; ++dy)
                #pragma unroll
                for (int dx = 0; dx < 3; ++dx)
                    xv[dy * 3 + dx] = sm[cc][ty + dy][tx + dx];
            const float* wt = wc + cc * 72;
            #pragma unroll
            for (int t = 0; t < 9; ++t) {
                float xt = xv[t];
                #pragma unroll
                for (int j = 0; j < 8; ++j)
                    acc[j] = fmaf(xt, wt[t * 8 + j], acc[j]);  // wt block-uniform -> s_load
            }
        }
    }

    int pix = h * WW + w;
    float a0 = avg[(size_t)(b * 2 + 0) * PIX + pix];
    float a1 = avg[(size_t)(b * 2 + 1) * PIX + pix];
    float bthr = bptr[0];

    float* ob = out + (size_t)b * CH * PIX + pix;
    #pragma unroll
    for (int j = 0; j < 8; j += 2) {
        int oc = ocg * 8 + j;
        float t0 = acc[j]     - a0 * S[oc]     - a1 * S[64 + oc]     + bias[oc];
        float t1 = acc[j + 1] - a0 * S[oc + 1] - a1 * S[64 + oc + 1] + bias[oc + 1];
        float n = sqrtf(t0 * t0 + t1 * t1);
        float r0, r1;
        if (n - bthr <= 0.f) { r0 = 0.f; r1 = 0.f; }
        else { r0 = t0 / n; r1 = t1 / n; }
        ob[(size_t)oc * PIX]       = r0 + a0;
        ob[(size_t)(oc + 1) * PIX] = r1 + a1;
    }
}

extern "C" void kernel_launch(void* const* d_in, const int* in_sizes, int n_in,
                              void* d_out, int out_size, void* d_ws, size_t ws_size,
                              hipStream_t stream) {
    const float* xx     = (const float*)d_in[0];
    const float* params = (const float*)d_in[1];
    const float* basis  = (const float*)d_in[2];
    const float* bias   = (const float*)d_in[3];
    const float* bptr   = (const float*)d_in[4];
    float* out = (float*)d_out;
    float* ws  = (float*)d_ws;

    float* Wl  = ws + OFF_WL;
    float* S   = ws + OFF_S;
    float* avg = ws + OFF_AVG;

    k_prep<<<657, 256, 0, stream>>>(params, basis, xx, Wl, S, avg);

    dim3 grid(64, 8, BN);
    k_main<<<grid, 256, 0, stream>>>(xx, Wl, S, bias, avg, bptr, out);
}

// Round 11
// 138.419 us; speedup vs baseline: 1.2567x; 1.2567x over previous
//
#include <hip/hip_runtime.h>

#define BN 4
#define CH 64          // CIN*UM = COUT*UM
#define HH 128
#define WW 128
#define PIX (HH*WW)

// workspace layout (float offsets)
#define OFF_WL  0                    // packed [4 ocg][64 c][9 tap][16 oc] = 36864
#define OFF_S   36864                // [2][64]      = 128
#define OFF_AVG 36992                // [4][2][128][128] = 131072

// LDS tile geometry: 8 channels x 18 rows x stride-24 (perfect 2-way banks)
#define SR 24
#define SCH (18*SR)        // 432 floats / channel
#define NCELL 324          // 18*18 halo cells
#define NSTAGE (8*NCELL)   // 2592

__device__ __forceinline__ int iclamp(int v, int lo, int hi) {
    return v < lo ? lo : (v > hi ? hi : v);
}

// ---- single prep kernel, 3 roles by block range:
//  [0,144)    : Wl packed [ocg][c][tap][16] ; ker[oc, c, p, q], tap = q*3+p
//  144        : S[u][oc] via factorized sum (== sum of ker over i,taps)
//  [145, 657) : avg[b][u][16x16 tile] via halo colsum + box3x3, /288
__global__ __launch_bounds__(256) void k_prep(const float* __restrict__ params,
                                              const float* __restrict__ basis,
                                              const float* __restrict__ x,
                                              float* __restrict__ Wl,
                                              float* __restrict__ S,
                                              float* __restrict__ avg) {
    int bx = blockIdx.x;
    if (bx < 144) {
        int idx = bx * 256 + threadIdx.x;      // < 36864
        int oc  = idx & 63;
        int tap = (idx >> 6) % 9;
        int c   = idx / 576;
        int q = tap / 3, p = tap % 3;
        int o = oc >> 1, g = oc & 1;
        int i = c >> 1, u = c & 1;
        float s = 0.f;
        #pragma unroll
        for (int n = 0; n < 4; ++n)
            #pragma unroll
            for (int d = 0; d < 4; ++d)
                s = fmaf(params[((o * 32 + i) * 4 + n) * 4 + d],
                         basis[((((n * 4 + d) * 3 + p) * 3 + q) * 2 + g) * 2 + u], s);
        // packed: [ocg][c][tap][oc&15]
        Wl[(((oc >> 4) * 64 + c) * 9 + tap) * 16 + (oc & 15)] = s;
    } else if (bx == 144) {
        int t = threadIdx.x;
        if (t < 128) {
            int u = t >> 6, oc = t & 63;
            int o = oc >> 1, g = oc & 1;
            float s = 0.f;
            #pragma unroll
            for (int nd = 0; nd < 16; ++nd) {
                int n = nd >> 2, d = nd & 3;
                float pa = 0.f;
                for (int i = 0; i < 32; ++i)
                    pa += params[((o * 32 + i) * 4 + n) * 4 + d];
                float sb = 0.f;
                #pragma unroll
                for (int e = 0; e < 3; ++e)
                    #pragma unroll
                    for (int f = 0; f < 3; ++f)
                        sb += basis[((((n * 4 + d) * 3 + e) * 3 + f) * 2 + g) * 2 + u];
                s = fmaf(pa, sb, s);
            }
            S[t] = s;
        }
    } else {
        // avg tile: id -> (b, u, tile)
        int id = bx - 145;                 // < 512
        int tile = id & 63;
        int u    = (id >> 6) & 1;
        int b    = id >> 7;
        int ty0 = (tile >> 3) * 16, tx0 = (tile & 7) * 16;

        __shared__ float hs[18][19];
        int t = threadIdx.x;
        for (int cell = t; cell < 324; cell += 256) {
            int hy = cell / 18, hx = cell - (cell / 18) * 18;
            int gy = iclamp(ty0 + hy - 1, 0, HH - 1);
            int gx = iclamp(tx0 + hx - 1, 0, WW - 1);
            const float* xp = x + ((size_t)b * CH + u) * PIX + gy * WW + gx;
            float s = 0.f;
            #pragma unroll
            for (int i = 0; i < 32; ++i) s += xp[(size_t)i * 2 * PIX];
            hs[hy][hx] = s;
        }
        __syncthreads();
        int py = t >> 4, px = t & 15;
        float s = hs[py][px]     + hs[py][px + 1]     + hs[py][px + 2]
                + hs[py + 1][px] + hs[py + 1][px + 1] + hs[py + 1][px + 2]
                + hs[py + 2][px] + hs[py + 2][px + 1] + hs[py + 2][px + 2];
        avg[(size_t)(b * 2 + u) * PIX + (ty0 + py) * WW + (tx0 + px)] = s * (1.0f / 288.0f);
    }
}

// ---- main: 16 oc/thread, LDS halo staging (stride-24, 8 ch/round),
//      precomputed staging offsets, round-ahead register prefetch
__global__ __launch_bounds__(256, 4) void k_main(
    const float* __restrict__ x,     // [4][64][128][128]
    const float* __restrict__ Wl,    // packed [4][64][9][16]
    const float* __restrict__ S,     // [2][64]
    const float* __restrict__ bias,  // [64]
    const float* __restrict__ avg,   // [4][2][128][128]
    const float* __restrict__ bptr,  // scalar b
    float* __restrict__ out)         // [4][64][128][128]
{
    __shared__ float sm[8 * SCH];    // 13824 B

    int tile = blockIdx.x;            // 8x8 tiles of 16x16
    int ocg  = blockIdx.y;            // 4 groups of 16 oc
    int b    = blockIdx.z;
    int ty = threadIdx.x >> 4, tx = threadIdx.x & 15;
    int h0 = (tile >> 3) * 16, w0 = (tile & 7) * 16;
    int h = h0 + ty, w = w0 + tx;

    const float* xb = x + (size_t)b * CH * PIX;

    // staging offsets are fixed across rounds: precompute once
    int goff[11], loff[11];
    #pragma unroll
    for (int k = 0; k < 11; ++k) {
        int cell = threadIdx.x + (k << 8);
        if (cell >= NSTAGE) cell = NSTAGE - 1;     // k=10 tail, guarded below
        int cc = cell / NCELL;
        int r  = cell - cc * NCELL;
        int hy = r / 18, hx = r - (r / 18) * 18;
        int gy = iclamp(h0 - 1 + hy, 0, HH - 1);
        int gx = iclamp(w0 - 1 + hx, 0, WW - 1);
        goff[k] = cc * PIX + gy * WW + gx;
        loff[k] = cc * SCH + hy * SR + hx;
    }
    bool act10 = threadIdx.x < (NSTAGE - 2560);    // tid < 32
    int lrd = ty * SR + tx;                        // LDS read base (floats)

    float acc[16];
    #pragma unroll
    for (int j = 0; j < 16; ++j) acc[j] = 0.f;

    // prologue: stage round 0
    {
        #pragma unroll
        for (int k = 0; k < 10; ++k) sm[loff[k]] = xb[goff[k]];
        if (act10) sm[loff[10]] = xb[goff[10]];
    }
    __syncthreads();

    const float* wbase = Wl + (size_t)ocg * 64 * 144;   // [c][tap][16]

    for (int c0 = 0; c0 < CH; c0 += 8) {
        // prefetch next round's cells into registers (hidden under FMAs)
        float xf[11];
        bool more = (c0 + 8 < CH);
        if (more) {
            const float* xn = xb + (size_t)(c0 + 8) * PIX;
            #pragma unroll
            for (int k = 0; k < 10; ++k) xf[k] = xn[goff[k]];
            if (act10) xf[10] = xn[goff[10]];
        }

        const float* wc = wbase + c0 * 144;
        #pragma unroll
        for (int cc = 0; cc < 8; ++cc) {
            float xv[9];
            #pragma unroll
            for (int dy = 0; dy < 3; ++dy)
                #pragma unroll
                for (int dx = 0; dx < 3; ++dx)
                    xv[dy * 3 + dx] = sm[lrd + cc * SCH + dy * SR + dx];
            const float* wt = wc + cc * 144;
            #pragma unroll
            for (int t = 0; t < 9; ++t) {
                float xt = xv[t];
                #pragma unroll
                for (int j = 0; j < 16; ++j)
                    acc[j] = fmaf(xt, wt[t * 16 + j], acc[j]);  // wt block-uniform -> s_load
            }
        }

        if (more) {
            __syncthreads();    // all reads of this round done
            #pragma unroll
            for (int k = 0; k < 10; ++k) sm[loff[k]] = xf[k];
            if (act10) sm[loff[10]] = xf[10];
            __syncthreads();    // writes visible
        }
    }

    int pix = h * WW + w;
    float a0 = avg[(size_t)(b * 2 + 0) * PIX + pix];
    float a1 = avg[(size_t)(b * 2 + 1) * PIX + pix];
    float bthr = bptr[0];

    float* ob = out + (size_t)b * CH * PIX + pix;
    #pragma unroll
    for (int j = 0; j < 16; j += 2) {
        int oc = ocg * 16 + j;
        float t0 = acc[j]     - a0 * S[oc]     - a1 * S[64 + oc]     + bias[oc];
        float t1 = acc[j + 1] - a0 * S[oc + 1] - a1 * S[64 + oc + 1] + bias[oc + 1];
        float n = sqrtf(t0 * t0 + t1 * t1);
        float r0, r1;
        if (n - bthr <= 0.f) { r0 = 0.f; r1 = 0.f; }
        else { r0 = t0 / n; r1 = t1 / n; }
        ob[(size_t)oc * PIX]       = r0 + a0;
        ob[(size_t)(oc + 1) * PIX] = r1 + a1;
    }
}

extern "C" void kernel_launch(void* const* d_in, const int* in_sizes, int n_in,
                              void* d_out, int out_size, void* d_ws, size_t ws_size,
                              hipStream_t stream) {
    const float* xx     = (const float*)d_in[0];
    const float* params = (const float*)d_in[1];
    const float* basis  = (const float*)d_in[2];
    const float* bias   = (const float*)d_in[3];
    const float* bptr   = (const float*)d_in[4];
    float* out = (float*)d_out;
    float* ws  = (float*)d_ws;

    float* Wl  = ws + OFF_WL;
    float* S   = ws + OFF_S;
    float* avg = ws + OFF_AVG;

    k_prep<<<657, 256, 0, stream>>>(params, basis, xx, Wl, S, avg);

    dim3 grid(64, 4, BN);
    k_main<<<grid, 256, 0, stream>>>(xx, Wl, S, bias, avg, bptr, out);
}